// Round 2
// baseline (4190.046 us; speedup 1.0000x reference)
//
#include <hip/hip_runtime.h>
#include <hip/hip_bf16.h>

#define FF 32   // input features
#define HF 24   // hidden features

// ---------- degree accumulation ----------
__global__ __launch_bounds__(256) void k_deg(
        const int* __restrict__ src, const int* __restrict__ dst,
        float* __restrict__ deg_out, float* __restrict__ deg_in, int E) {
    int e = blockIdx.x * blockDim.x + threadIdx.x;
    if (e < E) {
        atomicAdd(&deg_out[src[e]], 1.0f);
        atomicAdd(&deg_in[dst[e]], 1.0f);
    }
}

// ---------- deg -> rsqrt(max(deg,1)) in place ----------
__global__ __launch_bounds__(256) void k_norm(float* __restrict__ buf, int n) {
    int i = blockIdx.x * blockDim.x + threadIdx.x;
    if (i < n) {
        float v = buf[i];
        buf[i] = rsqrtf(fmaxf(v, 1.0f));
    }
}

// ---------- layer 1: x = (feats * norm_src) @ W1 ----------
__global__ __launch_bounds__(256) void k_layer1(
        const float* __restrict__ feats,
        const float* __restrict__ W1,
        const float* __restrict__ norm_src,
        float* __restrict__ x, int n) {
    __shared__ float sW[FF * HF];
    for (int i = threadIdx.x; i < FF * HF; i += blockDim.x)
        sW[i] = W1[i];
    __syncthreads();

    int node = blockIdx.x * blockDim.x + threadIdx.x;
    if (node >= n) return;

    float ns = norm_src[node];
    float f[FF];
    const float4* fr = reinterpret_cast<const float4*>(feats + (size_t)node * FF);
#pragma unroll
    for (int q = 0; q < FF / 4; q++) {
        float4 v = fr[q];
        f[4 * q + 0] = v.x * ns;
        f[4 * q + 1] = v.y * ns;
        f[4 * q + 2] = v.z * ns;
        f[4 * q + 3] = v.w * ns;
    }

    float acc[HF];
#pragma unroll
    for (int j = 0; j < HF; j++) acc[j] = 0.0f;
#pragma unroll
    for (int k = 0; k < FF; k++) {
        float fk = f[k];
#pragma unroll
        for (int j = 0; j < HF; j++) acc[j] += fk * sW[k * HF + j];
    }

    float4* xr = reinterpret_cast<float4*>(x + (size_t)node * HF);
#pragma unroll
    for (int q = 0; q < 6; q++)
        xr[q] = make_float4(acc[4 * q], acc[4 * q + 1], acc[4 * q + 2], acc[4 * q + 3]);
}

// ---------- scatter: agg[dst] += x[src] ----------
__global__ __launch_bounds__(256) void k_scatter(
        const int* __restrict__ src, const int* __restrict__ dst,
        const float* __restrict__ x, float* __restrict__ agg, int E) {
    int e = blockIdx.x * blockDim.x + threadIdx.x;
    if (e >= E) return;
    int s = src[e];
    int d = dst[e];
    const float4* xr = reinterpret_cast<const float4*>(x + (size_t)s * HF);
    float* ar = agg + (size_t)d * HF;
#pragma unroll
    for (int q = 0; q < 6; q++) {
        float4 v = xr[q];
        atomicAdd(ar + 4 * q + 0, v.x);
        atomicAdd(ar + 4 * q + 1, v.y);
        atomicAdd(ar + 4 * q + 2, v.z);
        atomicAdd(ar + 4 * q + 3, v.w);
    }
}

// ---------- layer 2: x = (relu(agg*norm_dst + b1) * norm_src) @ W2 ----------
__global__ __launch_bounds__(256) void k_layer2(
        const float* __restrict__ agg,
        const float* __restrict__ W2,
        const float* __restrict__ b1,
        const float* __restrict__ norm_src,
        const float* __restrict__ norm_dst,
        float* __restrict__ x, int n) {
    __shared__ float sW[HF * HF];
    __shared__ float sb[HF];
    for (int i = threadIdx.x; i < HF * HF; i += blockDim.x)
        sW[i] = W2[i];
    if (threadIdx.x < HF) sb[threadIdx.x] = b1[threadIdx.x];
    __syncthreads();

    int node = blockIdx.x * blockDim.x + threadIdx.x;
    if (node >= n) return;

    float nd = norm_dst[node];
    float ns = norm_src[node];

    float h[HF];
    const float4* ar = reinterpret_cast<const float4*>(agg + (size_t)node * HF);
#pragma unroll
    for (int q = 0; q < 6; q++) {
        float4 v = ar[q];
        h[4 * q + 0] = v.x;
        h[4 * q + 1] = v.y;
        h[4 * q + 2] = v.z;
        h[4 * q + 3] = v.w;
    }
#pragma unroll
    for (int j = 0; j < HF; j++)
        h[j] = fmaxf(h[j] * nd + sb[j], 0.0f) * ns;

    float acc[HF];
#pragma unroll
    for (int j = 0; j < HF; j++) acc[j] = 0.0f;
#pragma unroll
    for (int k = 0; k < HF; k++) {
        float hk = h[k];
#pragma unroll
        for (int j = 0; j < HF; j++) acc[j] += hk * sW[k * HF + j];
    }

    float4* xr = reinterpret_cast<float4*>(x + (size_t)node * HF);
#pragma unroll
    for (int q = 0; q < 6; q++)
        xr[q] = make_float4(acc[4 * q], acc[4 * q + 1], acc[4 * q + 2], acc[4 * q + 3]);
}

// ---------- final: out[r] = relu(agg*norm_dst + b2).reshape(.,96) @ Wd + bd ----------
__global__ __launch_bounds__(256) void k_final(
        const float* __restrict__ agg,
        const float* __restrict__ b2,
        const float* __restrict__ Wd,
        const float* __restrict__ bd,
        const float* __restrict__ norm_dst,
        float* __restrict__ out, int m) {
    __shared__ float sWd[4 * HF];
    __shared__ float sb[HF];
    __shared__ float sbd;
    for (int i = threadIdx.x; i < 4 * HF; i += blockDim.x)
        sWd[i] = Wd[i];
    if (threadIdx.x < HF) sb[threadIdx.x] = b2[threadIdx.x];
    if (threadIdx.x == 0) sbd = bd[0];
    __syncthreads();

    int r = blockIdx.x * blockDim.x + threadIdx.x;
    if (r >= m) return;

    float acc = sbd;
#pragma unroll
    for (int q = 0; q < 4; q++) {
        int node = 4 * r + q;
        float nd = norm_dst[node];
        const float4* ar = reinterpret_cast<const float4*>(agg + (size_t)node * HF);
#pragma unroll
        for (int p = 0; p < 6; p++) {
            float4 v = ar[p];
            acc += fmaxf(v.x * nd + sb[4 * p + 0], 0.0f) * sWd[q * HF + 4 * p + 0];
            acc += fmaxf(v.y * nd + sb[4 * p + 1], 0.0f) * sWd[q * HF + 4 * p + 1];
            acc += fmaxf(v.z * nd + sb[4 * p + 2], 0.0f) * sWd[q * HF + 4 * p + 2];
            acc += fmaxf(v.w * nd + sb[4 * p + 3], 0.0f) * sWd[q * HF + 4 * p + 3];
        }
    }
    out[r] = acc;
}

extern "C" void kernel_launch(void* const* d_in, const int* in_sizes, int n_in,
                              void* d_out, int out_size, void* d_ws, size_t ws_size,
                              hipStream_t stream) {
    const float* feats = (const float*)d_in[0];
    const int* src = (const int*)d_in[1];
    const int* dst = (const int*)d_in[2];
    const float* W1 = (const float*)d_in[3];
    const float* b1 = (const float*)d_in[4];
    const float* W2 = (const float*)d_in[5];
    const float* b2 = (const float*)d_in[6];
    const float* Wd = (const float*)d_in[7];
    const float* bd = (const float*)d_in[8];
    float* out = (float*)d_out;

    const int N = in_sizes[0] / FF;   // 200000
    const int E = in_sizes[1];        // 1600000
    const int M = out_size;           // N/4

    float* ws = (float*)d_ws;
    float* norm_src = ws;                               // N
    float* norm_dst = ws + N;                           // N
    float* agg = ws + 2 * (size_t)N;                    // 24N
    float* x   = ws + (2 + HF) * (size_t)N;             // 24N
    // total: 50N floats = 40 MB

    // zero degree + agg accumulators (ws is poisoned 0xAA each call)
    hipMemsetAsync(ws, 0, (size_t)(2 + HF) * N * sizeof(float), stream);

    k_deg<<<(E + 255) / 256, 256, 0, stream>>>(src, dst, norm_src, norm_dst, E);
    k_norm<<<(2 * N + 255) / 256, 256, 0, stream>>>(ws, 2 * N);
    k_layer1<<<(N + 255) / 256, 256, 0, stream>>>(feats, W1, norm_src, x, N);
    k_scatter<<<(E + 255) / 256, 256, 0, stream>>>(src, dst, x, agg, E);
    k_layer2<<<(N + 255) / 256, 256, 0, stream>>>(agg, W2, b1, norm_src, norm_dst, x, N);
    hipMemsetAsync(agg, 0, (size_t)HF * N * sizeof(float), stream);
    k_scatter<<<(E + 255) / 256, 256, 0, stream>>>(src, dst, x, agg, E);
    k_final<<<(M + 255) / 256, 256, 0, stream>>>(agg, b2, Wd, bd, norm_dst, out, M);
}

// Round 3
// 482.837 us; speedup vs baseline: 8.6780x; 8.6780x over previous
//
#include <hip/hip_runtime.h>
#include <hip/hip_bf16.h>

#define FF 32    // input features
#define HF 24    // hidden features
#define SCAN_B 256

// ---------- histogram: out-degree (float, into norm_src) + in-degree (int) ----------
__global__ __launch_bounds__(256) void k_hist(
        const int* __restrict__ src, const int* __restrict__ dst,
        float* __restrict__ degout_f, int* __restrict__ deg_in, int E) {
    int e = blockIdx.x * blockDim.x + threadIdx.x;
    if (e < E) {
        atomicAdd(&degout_f[src[e]], 1.0f);
        atomicAdd(&deg_in[dst[e]], 1);
    }
}

// ---------- in-place rsqrt(max(v,1)) ----------
__global__ __launch_bounds__(256) void k_rsqrt(float* __restrict__ buf, int n) {
    int i = blockIdx.x * blockDim.x + threadIdx.x;
    if (i < n) buf[i] = rsqrtf(fmaxf(buf[i], 1.0f));
}

// ---------- scan step 1: per-block exclusive scan of deg -> offs, block totals ----------
__global__ __launch_bounds__(SCAN_B) void k_scan1(
        const int* __restrict__ deg, int* __restrict__ offs,
        int* __restrict__ bsums, int n) {
    __shared__ int s[SCAN_B];
    int i = blockIdx.x * SCAN_B + threadIdx.x;
    int v = (i < n) ? deg[i] : 0;
    s[threadIdx.x] = v;
    __syncthreads();
    for (int off = 1; off < SCAN_B; off <<= 1) {
        int t = (threadIdx.x >= off) ? s[threadIdx.x - off] : 0;
        __syncthreads();
        s[threadIdx.x] += t;
        __syncthreads();
    }
    if (i < n) offs[i] = s[threadIdx.x] - v;       // exclusive
    if (threadIdx.x == SCAN_B - 1) bsums[blockIdx.x] = s[threadIdx.x];
}

// ---------- scan step 2: exclusive scan of block sums (nb <= 1024), single block ----------
__global__ __launch_bounds__(1024) void k_scan2(int* __restrict__ bsums, int nb) {
    __shared__ int s[1024];
    int v = (threadIdx.x < nb) ? bsums[threadIdx.x] : 0;
    s[threadIdx.x] = v;
    __syncthreads();
    for (int off = 1; off < 1024; off <<= 1) {
        int t = (threadIdx.x >= off) ? s[threadIdx.x - off] : 0;
        __syncthreads();
        s[threadIdx.x] += t;
        __syncthreads();
    }
    if (threadIdx.x < nb) bsums[threadIdx.x] = s[threadIdx.x] - v;
}

// ---------- scan step 3: add block offsets ----------
__global__ __launch_bounds__(SCAN_B) void k_scan3(
        int* __restrict__ offs, const int* __restrict__ bsums, int n) {
    int i = blockIdx.x * SCAN_B + threadIdx.x;
    if (i < n) offs[i] += bsums[blockIdx.x];
}

// ---------- CSR fill: esrc sorted by dst; offs[d] becomes segment END after this ----------
__global__ __launch_bounds__(256) void k_fill(
        const int* __restrict__ src, const int* __restrict__ dst,
        int* __restrict__ offs, int* __restrict__ esrc, int E) {
    int e = blockIdx.x * blockDim.x + threadIdx.x;
    if (e < E) {
        int pos = atomicAdd(&offs[dst[e]], 1);
        esrc[pos] = src[e];
    }
}

// ---------- layer 1: x = (feats * norm_src) @ W1 ----------
__global__ __launch_bounds__(256) void k_layer1(
        const float* __restrict__ feats,
        const float* __restrict__ W1,
        const float* __restrict__ norm_src,
        float* __restrict__ x, int n) {
    __shared__ float sW[FF * HF];
    for (int i = threadIdx.x; i < FF * HF; i += blockDim.x) sW[i] = W1[i];
    __syncthreads();

    int node = blockIdx.x * blockDim.x + threadIdx.x;
    if (node >= n) return;

    float ns = norm_src[node];
    float f[FF];
    const float4* fr = reinterpret_cast<const float4*>(feats + (size_t)node * FF);
#pragma unroll
    for (int q = 0; q < FF / 4; q++) {
        float4 v = fr[q];
        f[4 * q + 0] = v.x * ns;
        f[4 * q + 1] = v.y * ns;
        f[4 * q + 2] = v.z * ns;
        f[4 * q + 3] = v.w * ns;
    }
    float acc[HF];
#pragma unroll
    for (int j = 0; j < HF; j++) acc[j] = 0.0f;
#pragma unroll
    for (int k = 0; k < FF; k++) {
        float fk = f[k];
#pragma unroll
        for (int j = 0; j < HF; j++) acc[j] += fk * sW[k * HF + j];
    }
    float4* xr = reinterpret_cast<float4*>(x + (size_t)node * HF);
#pragma unroll
    for (int q = 0; q < 6; q++)
        xr[q] = make_float4(acc[4 * q], acc[4 * q + 1], acc[4 * q + 2], acc[4 * q + 3]);
}

// ---------- gather-aggregate: agg[n] = (sum_{e in CSR[n]} x[esrc[e]]) * rsqrt(deg[n]) ----------
// 8 lanes per node; lane slot handles columns {slot, slot+8, slot+16} so each
// k-iteration's 8-lane read of a row is one 32B sector.
__global__ __launch_bounds__(256) void k_agg(
        const int* __restrict__ esrc, const int* __restrict__ offs,
        const int* __restrict__ deg_in,
        const float* __restrict__ x, float* __restrict__ agg, int n) {
    int t = blockIdx.x * blockDim.x + threadIdx.x;
    int node = t >> 3;
    int slot = t & 7;
    if (node >= n) return;

    int start = (node == 0) ? 0 : offs[node - 1];  // post-fill: offs[d] = end of segment d
    int end = offs[node];

    float a0 = 0.0f, a1 = 0.0f, a2 = 0.0f;
    for (int e = start; e < end; e++) {
        int s = esrc[e];
        const float* row = x + (size_t)s * HF + slot;
        a0 += row[0];
        a1 += row[8];
        a2 += row[16];
    }
    float nd = rsqrtf(fmaxf((float)deg_in[node], 1.0f));
    float* ar = agg + (size_t)node * HF + slot;
    ar[0]  = a0 * nd;
    ar[8]  = a1 * nd;
    ar[16] = a2 * nd;
}

// ---------- layer 2: x2 = (relu(agg + b1) * norm_src) @ W2   (norm_dst already folded) ----------
__global__ __launch_bounds__(256) void k_layer2(
        const float* __restrict__ agg,
        const float* __restrict__ W2,
        const float* __restrict__ b1,
        const float* __restrict__ norm_src,
        float* __restrict__ x, int n) {
    __shared__ float sW[HF * HF];
    __shared__ float sb[HF];
    for (int i = threadIdx.x; i < HF * HF; i += blockDim.x) sW[i] = W2[i];
    if (threadIdx.x < HF) sb[threadIdx.x] = b1[threadIdx.x];
    __syncthreads();

    int node = blockIdx.x * blockDim.x + threadIdx.x;
    if (node >= n) return;

    float ns = norm_src[node];
    float h[HF];
    const float4* ar = reinterpret_cast<const float4*>(agg + (size_t)node * HF);
#pragma unroll
    for (int q = 0; q < 6; q++) {
        float4 v = ar[q];
        h[4 * q + 0] = v.x;
        h[4 * q + 1] = v.y;
        h[4 * q + 2] = v.z;
        h[4 * q + 3] = v.w;
    }
#pragma unroll
    for (int j = 0; j < HF; j++)
        h[j] = fmaxf(h[j] + sb[j], 0.0f) * ns;

    float acc[HF];
#pragma unroll
    for (int j = 0; j < HF; j++) acc[j] = 0.0f;
#pragma unroll
    for (int k = 0; k < HF; k++) {
        float hk = h[k];
#pragma unroll
        for (int j = 0; j < HF; j++) acc[j] += hk * sW[k * HF + j];
    }
    float4* xr = reinterpret_cast<float4*>(x + (size_t)node * HF);
#pragma unroll
    for (int q = 0; q < 6; q++)
        xr[q] = make_float4(acc[4 * q], acc[4 * q + 1], acc[4 * q + 2], acc[4 * q + 3]);
}

// ---------- final: out[r] = relu(agg + b2).reshape(.,96) @ Wd + bd  (norm_dst folded) ----------
__global__ __launch_bounds__(256) void k_final(
        const float* __restrict__ agg,
        const float* __restrict__ b2,
        const float* __restrict__ Wd,
        const float* __restrict__ bd,
        float* __restrict__ out, int m) {
    __shared__ float sWd[4 * HF];
    __shared__ float sb[HF];
    __shared__ float sbd;
    for (int i = threadIdx.x; i < 4 * HF; i += blockDim.x) sWd[i] = Wd[i];
    if (threadIdx.x < HF) sb[threadIdx.x] = b2[threadIdx.x];
    if (threadIdx.x == 0) sbd = bd[0];
    __syncthreads();

    int r = blockIdx.x * blockDim.x + threadIdx.x;
    if (r >= m) return;

    float acc = sbd;
#pragma unroll
    for (int q = 0; q < 4; q++) {
        int node = 4 * r + q;
        const float4* ar = reinterpret_cast<const float4*>(agg + (size_t)node * HF);
#pragma unroll
        for (int p = 0; p < 6; p++) {
            float4 v = ar[p];
            acc += fmaxf(v.x + sb[4 * p + 0], 0.0f) * sWd[q * HF + 4 * p + 0];
            acc += fmaxf(v.y + sb[4 * p + 1], 0.0f) * sWd[q * HF + 4 * p + 1];
            acc += fmaxf(v.z + sb[4 * p + 2], 0.0f) * sWd[q * HF + 4 * p + 2];
            acc += fmaxf(v.w + sb[4 * p + 3], 0.0f) * sWd[q * HF + 4 * p + 3];
        }
    }
    out[r] = acc;
}

extern "C" void kernel_launch(void* const* d_in, const int* in_sizes, int n_in,
                              void* d_out, int out_size, void* d_ws, size_t ws_size,
                              hipStream_t stream) {
    const float* feats = (const float*)d_in[0];
    const int* src = (const int*)d_in[1];
    const int* dst = (const int*)d_in[2];
    const float* W1 = (const float*)d_in[3];
    const float* b1 = (const float*)d_in[4];
    const float* W2 = (const float*)d_in[5];
    const float* b2 = (const float*)d_in[6];
    const float* Wd = (const float*)d_in[7];
    const float* bd = (const float*)d_in[8];
    float* out = (float*)d_out;

    const int N = in_sizes[0] / FF;   // 200000
    const int E = in_sizes[1];        // 1600000
    const int M = out_size;           // N/4

    // workspace layout (element offsets, 4B each)
    float* ws = (float*)d_ws;
    float* norm_src = ws;                                 // N floats
    int* deg_in     = (int*)(ws + N);                     // N ints
    int* offs       = (int*)(ws + 2 * (size_t)N);         // N ints
    int* bsums      = (int*)(ws + 3 * (size_t)N);         // 1024 ints
    int* esrc       = (int*)(ws + 3 * (size_t)N + 1024);  // E ints
    float* agg      = ws + 3 * (size_t)N + 1024 + E;      // 24N floats
    float* x        = agg + (size_t)HF * N;               // 24N floats
    // total: 51N + E + 1024 elems  ~= 47.2 MB

    const int nbE = (E + 255) / 256;
    const int nbN = (N + 255) / 256;
    const int nbScan = (N + SCAN_B - 1) / SCAN_B;         // 782 <= 1024

    // zero degree arrays (ws is poisoned 0xAA each call)
    hipMemsetAsync(ws, 0, 2 * (size_t)N * sizeof(float), stream);

    k_hist<<<nbE, 256, 0, stream>>>(src, dst, norm_src, deg_in, E);
    k_scan1<<<nbScan, SCAN_B, 0, stream>>>(deg_in, offs, bsums, N);
    k_scan2<<<1, 1024, 0, stream>>>(bsums, nbScan);
    k_scan3<<<nbScan, SCAN_B, 0, stream>>>(offs, bsums, N);
    k_rsqrt<<<nbN, 256, 0, stream>>>(norm_src, N);
    k_layer1<<<nbN, 256, 0, stream>>>(feats, W1, norm_src, x, N);
    k_fill<<<nbE, 256, 0, stream>>>(src, dst, offs, esrc, E);
    k_agg<<<(8 * N + 255) / 256, 256, 0, stream>>>(esrc, offs, deg_in, x, agg, N);
    k_layer2<<<nbN, 256, 0, stream>>>(agg, W2, b1, norm_src, x, N);
    k_agg<<<(8 * N + 255) / 256, 256, 0, stream>>>(esrc, offs, deg_in, x, agg, N);
    k_final<<<(M + 255) / 256, 256, 0, stream>>>(agg, b2, Wd, bd, out, M);
}

// Round 4
// 454.619 us; speedup vs baseline: 9.2166x; 1.0621x over previous
//
#include <hip/hip_runtime.h>

#define FF 32    // input features
#define HF 24    // hidden features
#define SCAN_B 256
#define NXCD 8
#define AGG_NODES 32   // nodes per block in agg kernels (192 threads = 32 nodes x 6 lanes)

__device__ __forceinline__ unsigned xcc_id() {
    unsigned x;
    asm volatile("s_getreg_b32 %0, hwreg(HW_REG_XCC_ID)" : "=s"(x));
    return x & (NXCD - 1);
}

// ---------- histogram into per-XCD partial counters (L2-local atomics) ----------
// hist8 layout: [c*N + i] = out-degree partial on XCD c; [(8+c)*N + i] = in-degree partial.
__global__ __launch_bounds__(256) void k_hist(
        const int* __restrict__ src, const int* __restrict__ dst,
        int* __restrict__ hist8, int N, int E) {
    unsigned c = xcc_id();
    int* dout = hist8 + (size_t)c * N;
    int* din  = hist8 + (size_t)(NXCD + c) * N;
    int e = blockIdx.x * blockDim.x + threadIdx.x;
    if (e < E) {
        __hip_atomic_fetch_add(&dout[src[e]], 1, __ATOMIC_RELAXED, __HIP_MEMORY_SCOPE_WORKGROUP);
        __hip_atomic_fetch_add(&din[dst[e]],  1, __ATOMIC_RELAXED, __HIP_MEMORY_SCOPE_WORKGROUP);
    }
}

// ---------- reduce 8 partials -> norm_src (rsqrt), deg_in (int) ----------
__global__ __launch_bounds__(256) void k_reduce(
        const int* __restrict__ hist8, float* __restrict__ norm_src,
        int* __restrict__ deg_in, int n) {
    int i = blockIdx.x * blockDim.x + threadIdx.x;
    if (i >= n) return;
    int s0 = 0, s1 = 0;
#pragma unroll
    for (int c = 0; c < NXCD; c++) {
        s0 += hist8[(size_t)c * n + i];
        s1 += hist8[(size_t)(NXCD + c) * n + i];
    }
    norm_src[i] = rsqrtf(fmaxf((float)s0, 1.0f));
    deg_in[i] = s1;
}

// ---------- scan step 1: per-block exclusive scan of deg -> offs, block totals ----------
__global__ __launch_bounds__(SCAN_B) void k_scan1(
        const int* __restrict__ deg, int* __restrict__ offs,
        int* __restrict__ bsums, int n) {
    __shared__ int s[SCAN_B];
    int i = blockIdx.x * SCAN_B + threadIdx.x;
    int v = (i < n) ? deg[i] : 0;
    s[threadIdx.x] = v;
    __syncthreads();
    for (int off = 1; off < SCAN_B; off <<= 1) {
        int t = (threadIdx.x >= off) ? s[threadIdx.x - off] : 0;
        __syncthreads();
        s[threadIdx.x] += t;
        __syncthreads();
    }
    if (i < n) offs[i] = s[threadIdx.x] - v;       // exclusive
    if (threadIdx.x == SCAN_B - 1) bsums[blockIdx.x] = s[threadIdx.x];
}

// ---------- scan step 2: exclusive scan of block sums (nb <= 1024), single block ----------
__global__ __launch_bounds__(1024) void k_scan2(int* __restrict__ bsums, int nb) {
    __shared__ int s[1024];
    int v = (threadIdx.x < nb) ? bsums[threadIdx.x] : 0;
    s[threadIdx.x] = v;
    __syncthreads();
    for (int off = 1; off < 1024; off <<= 1) {
        int t = (threadIdx.x >= off) ? s[threadIdx.x - off] : 0;
        __syncthreads();
        s[threadIdx.x] += t;
        __syncthreads();
    }
    if (threadIdx.x < nb) bsums[threadIdx.x] = s[threadIdx.x] - v;
}

// ---------- scan step 3: add block offsets ----------
__global__ __launch_bounds__(SCAN_B) void k_scan3(
        int* __restrict__ offs, const int* __restrict__ bsums, int n) {
    int i = blockIdx.x * SCAN_B + threadIdx.x;
    if (i < n) offs[i] += bsums[blockIdx.x];
}

// ---------- CSR fill: esrc sorted by dst; offs[d] becomes segment END after this ----------
__global__ __launch_bounds__(256) void k_fill(
        const int* __restrict__ src, const int* __restrict__ dst,
        int* __restrict__ offs, int* __restrict__ esrc, int E) {
    int e = blockIdx.x * blockDim.x + threadIdx.x;
    if (e < E) {
        int pos = atomicAdd(&offs[dst[e]], 1);   // must be device scope (global cursor)
        esrc[pos] = src[e];
    }
}

// ---------- layer 1: x = (feats * norm_src) @ W1 ----------
__global__ __launch_bounds__(256) void k_layer1(
        const float* __restrict__ feats,
        const float* __restrict__ W1,
        const float* __restrict__ norm_src,
        float* __restrict__ x, int n) {
    __shared__ float sW[FF * HF];
    for (int i = threadIdx.x; i < FF * HF; i += blockDim.x) sW[i] = W1[i];
    __syncthreads();

    int node = blockIdx.x * blockDim.x + threadIdx.x;
    if (node >= n) return;

    float ns = norm_src[node];
    float f[FF];
    const float4* fr = reinterpret_cast<const float4*>(feats + (size_t)node * FF);
#pragma unroll
    for (int q = 0; q < FF / 4; q++) {
        float4 v = fr[q];
        f[4 * q + 0] = v.x * ns;
        f[4 * q + 1] = v.y * ns;
        f[4 * q + 2] = v.z * ns;
        f[4 * q + 3] = v.w * ns;
    }
    float acc[HF];
#pragma unroll
    for (int j = 0; j < HF; j++) acc[j] = 0.0f;
#pragma unroll
    for (int k = 0; k < FF; k++) {
        float fk = f[k];
#pragma unroll
        for (int j = 0; j < HF; j++) acc[j] += fk * sW[k * HF + j];
    }
    float4* xr = reinterpret_cast<float4*>(x + (size_t)node * HF);
#pragma unroll
    for (int q = 0; q < 6; q++)
        xr[q] = make_float4(acc[4 * q], acc[4 * q + 1], acc[4 * q + 2], acc[4 * q + 3]);
}

// ---------- fused: aggregate (CSR gather) + relu(.*nd + b1)*ns @ W2 -> x_out ----------
// 6 lanes per node, each lane owns 4 contiguous columns (one float4).
__global__ __launch_bounds__(192) void k_agg_l2(
        const int* __restrict__ esrc, const int* __restrict__ offs,
        const float* __restrict__ norm_src,
        const float* __restrict__ W2, const float* __restrict__ b1,
        const float* __restrict__ x_in, float* __restrict__ x_out, int n) {
    __shared__ float sW[HF * HF];
    __shared__ float sh[AGG_NODES][HF + 1];
    int tid = threadIdx.x;
    for (int i = tid; i < HF * HF; i += 192) sW[i] = W2[i];

    int ln = tid / 6, slot = tid % 6;
    int node = blockIdx.x * AGG_NODES + ln;

    float4 acc = make_float4(0.f, 0.f, 0.f, 0.f);
    int start = 0, end = 0;
    if (node < n) {
        start = (node == 0) ? 0 : offs[node - 1];   // post-fill: offs[d] = segment end
        end = offs[node];
    }
    for (int e = start; e < end; e++) {
        int s = esrc[e];
        const float4* row = reinterpret_cast<const float4*>(x_in + (size_t)s * HF);
        float4 v = row[slot];
        acc.x += v.x; acc.y += v.y; acc.z += v.z; acc.w += v.w;
    }
    if (node < n) {
        float nd = rsqrtf(fmaxf((float)(end - start), 1.0f));
        float ns = norm_src[node];
        float4 bv = reinterpret_cast<const float4*>(b1)[slot];
        sh[ln][slot * 4 + 0] = fmaxf(acc.x * nd + bv.x, 0.f) * ns;
        sh[ln][slot * 4 + 1] = fmaxf(acc.y * nd + bv.y, 0.f) * ns;
        sh[ln][slot * 4 + 2] = fmaxf(acc.z * nd + bv.z, 0.f) * ns;
        sh[ln][slot * 4 + 3] = fmaxf(acc.w * nd + bv.w, 0.f) * ns;
    }
    __syncthreads();   // covers both sW staging and sh writes

    if (node >= n) return;
    float o0 = 0.f, o1 = 0.f, o2 = 0.f, o3 = 0.f;
    int j = slot * 4;
#pragma unroll
    for (int k = 0; k < HF; k++) {
        float hk = sh[ln][k];
        o0 += hk * sW[k * HF + j + 0];
        o1 += hk * sW[k * HF + j + 1];
        o2 += hk * sW[k * HF + j + 2];
        o3 += hk * sW[k * HF + j + 3];
    }
    reinterpret_cast<float4*>(x_out + (size_t)node * HF)[slot] = make_float4(o0, o1, o2, o3);
}

// ---------- fused: aggregate (CSR gather) + relu(.*nd + b2) @ Wd + bd -> out ----------
__global__ __launch_bounds__(192) void k_agg_fin(
        const int* __restrict__ esrc, const int* __restrict__ offs,
        const float* __restrict__ Wd, const float* __restrict__ b2,
        const float* __restrict__ bd,
        const float* __restrict__ x_in, float* __restrict__ out, int n, int m) {
    __shared__ float sOut[AGG_NODES / 4];   // 8 output rows per block
    int tid = threadIdx.x;
    if (tid < AGG_NODES / 4) sOut[tid] = 0.f;

    int ln = tid / 6, slot = tid % 6;
    int node = blockIdx.x * AGG_NODES + ln;

    float4 acc = make_float4(0.f, 0.f, 0.f, 0.f);
    int start = 0, end = 0;
    if (node < n) {
        start = (node == 0) ? 0 : offs[node - 1];
        end = offs[node];
    }
    for (int e = start; e < end; e++) {
        int s = esrc[e];
        const float4* row = reinterpret_cast<const float4*>(x_in + (size_t)s * HF);
        float4 v = row[slot];
        acc.x += v.x; acc.y += v.y; acc.z += v.z; acc.w += v.w;
    }
    float partial = 0.f;
    if (node < n) {
        float nd = rsqrtf(fmaxf((float)(end - start), 1.0f));
        float4 bv = reinterpret_cast<const float4*>(b2)[slot];
        float4 wv = reinterpret_cast<const float4*>(Wd)[(node & 3) * 6 + slot];
        partial  = fmaxf(acc.x * nd + bv.x, 0.f) * wv.x;
        partial += fmaxf(acc.y * nd + bv.y, 0.f) * wv.y;
        partial += fmaxf(acc.z * nd + bv.z, 0.f) * wv.z;
        partial += fmaxf(acc.w * nd + bv.w, 0.f) * wv.w;
    }
    __syncthreads();   // sOut zeroed
    if (node < n) atomicAdd(&sOut[ln >> 2], partial);   // LDS atomic
    __syncthreads();
    int row = blockIdx.x * (AGG_NODES / 4) + tid;
    if (tid < AGG_NODES / 4 && row < m) out[row] = sOut[tid] + bd[0];
}

extern "C" void kernel_launch(void* const* d_in, const int* in_sizes, int n_in,
                              void* d_out, int out_size, void* d_ws, size_t ws_size,
                              hipStream_t stream) {
    const float* feats = (const float*)d_in[0];
    const int* src = (const int*)d_in[1];
    const int* dst = (const int*)d_in[2];
    const float* W1 = (const float*)d_in[3];
    const float* b1 = (const float*)d_in[4];
    const float* W2 = (const float*)d_in[5];
    const float* b2 = (const float*)d_in[6];
    const float* Wd = (const float*)d_in[7];
    const float* bd = (const float*)d_in[8];
    float* out = (float*)d_out;

    const int N = in_sizes[0] / FF;   // 200000
    const int E = in_sizes[1];        // 1600000
    const int M = out_size;           // N/4

    // workspace layout (4B elems), total 51N + 1024 + E ~= 47.2 MB
    float* ws = (float*)d_ws;
    float* norm_src = ws;                                   // N
    int* deg_in     = (int*)(ws + N);                       // N
    int* offs       = (int*)(ws + 2 * (size_t)N);           // N
    int* bsums      = (int*)(ws + 3 * (size_t)N);           // 1024
    int* esrc       = (int*)(ws + 3 * (size_t)N + 1024);    // E
    float* x2       = ws + 3 * (size_t)N + 1024 + E;        // 24N (first 16N doubles as hist8)
    int* hist8      = (int*)x2;                             // 16N (dead after k_reduce)
    float* x1       = x2 + (size_t)HF * N;                  // 24N

    const int nbE = (E + 255) / 256;
    const int nbN = (N + 255) / 256;
    const int nbScan = (N + SCAN_B - 1) / SCAN_B;           // 782 <= 1024
    const int nbAgg = (N + AGG_NODES - 1) / AGG_NODES;      // 6250

    // zero the per-XCD histograms (ws is poisoned 0xAA each call)
    hipMemsetAsync(hist8, 0, (size_t)2 * NXCD * N * sizeof(int), stream);

    k_hist<<<nbE, 256, 0, stream>>>(src, dst, hist8, N, E);
    k_reduce<<<nbN, 256, 0, stream>>>(hist8, norm_src, deg_in, N);
    k_scan1<<<nbScan, SCAN_B, 0, stream>>>(deg_in, offs, bsums, N);
    k_scan2<<<1, 1024, 0, stream>>>(bsums, nbScan);
    k_scan3<<<nbScan, SCAN_B, 0, stream>>>(offs, bsums, N);
    k_layer1<<<nbN, 256, 0, stream>>>(feats, W1, norm_src, x1, N);
    k_fill<<<nbE, 256, 0, stream>>>(src, dst, offs, esrc, E);
    k_agg_l2<<<nbAgg, 192, 0, stream>>>(esrc, offs, norm_src, W2, b1, x1, x2, N);
    k_agg_fin<<<nbAgg, 192, 0, stream>>>(esrc, offs, Wd, b2, bd, x2, out, N, M);
}